// Round 2
// baseline (359.101 us; speedup 1.0000x reference)
//
#include <hip/hip_runtime.h>
#include <hip/hip_bf16.h>
#include <stdint.h>

#define SS 8192
#define DD 1024
#define RR 16
#define OO 512

typedef __bf16 bf16_8 __attribute__((ext_vector_type(8)));
typedef __bf16 bf16_4 __attribute__((ext_vector_type(4)));
typedef float f32_4 __attribute__((ext_vector_type(4)));

typedef __attribute__((address_space(1))) void g1_void;
typedef __attribute__((address_space(3))) void lds_void;

#define L2E 1.44269504f

__device__ __forceinline__ void gload_lds16(const void* g, void* l) {
  __builtin_amdgcn_global_load_lds((g1_void*)(uintptr_t)g,
                                   (lds_void*)(uint32_t)(uintptr_t)l, 16, 0, 0);
}

__global__ void somfnn_cvt(const float* __restrict__ src, __bf16* __restrict__ dst, int n4) {
  int i = blockIdx.x * blockDim.x + threadIdx.x;
  if (i >= n4) return;
  float4 v = ((const float4*)src)[i];
  bf16_4 o;
  o[0] = (__bf16)v.x; o[1] = (__bf16)v.y; o[2] = (__bf16)v.z; o[3] = (__bf16)v.w;
  ((bf16_4*)dst)[i] = o;
}

// MODE 0: fused  — phase1 cvt fp32->bf16 into ws + zero out, grid barrier,
//                  then bf16 GEMM from ws. Requires all 512 blocks co-resident
//                  (72KB LDS -> exactly 2 blocks/CU -> grid 512 == capacity).
// MODE 1: preconv — bf16 GEMM from ws (separate cvt kernels ran before).
// MODE 2: fallback — fp32 inputs, convert during LDS staging (correctness path).
template <int MODE>
__global__ __launch_bounds__(256, 2) void somfnn_gemm(
    const void* __restrict__ Xp, const void* __restrict__ Wp,
    const float* __restrict__ bias_g, const float* __restrict__ lam_g,
    float* __restrict__ out,
    const float* __restrict__ Xf32, const float* __restrict__ Wf32,
    unsigned int* __restrict__ ctr) {
  constexpr int BM = 128, BN = 128, BK = 64;
  constexpr int TILE = BM * BK;          // 8192 bf16 = 16KB
  constexpr int NSTEP = 8 * (DD / BK);   // 8 rules * 16 k-tiles = 128

  __shared__ __align__(16) __bf16 lds_a[2][TILE];
  __shared__ __align__(16) __bf16 lds_b[2][TILE];
  __shared__ float lds_bias[8 * BN];   // pre-scaled: -b * log2(e)
  __shared__ float lds_lam[8 * BM];

  const int tid = threadIdx.x;
  const int bid = blockIdx.x;

  if constexpr (MODE == 0) {
    // ---- phase 1: convert this block's 1/512 slice of X|W, zero out slice ----
    {
      const float4* src;
      bf16_4* dst;
      if (bid < 256) {
        src = (const float4*)Xf32 + (size_t)bid * 8192;
        dst = (bf16_4*)Xp + (size_t)bid * 8192;
      } else {
        src = (const float4*)Wf32 + (size_t)(bid - 256) * 8192;
        dst = (bf16_4*)Wp + (size_t)(bid - 256) * 8192;
      }
#pragma unroll
      for (int it = 0; it < 32; ++it) {
        int i = it * 256 + tid;
        float4 v = src[i];
        bf16_4 o;
        o[0] = (__bf16)v.x; o[1] = (__bf16)v.y; o[2] = (__bf16)v.z; o[3] = (__bf16)v.w;
        dst[i] = o;
      }
      float4* oz = (float4*)out + (size_t)bid * 2048;
      float4 z{0.f, 0.f, 0.f, 0.f};
#pragma unroll
      for (int it = 0; it < 8; ++it) oz[it * 256 + tid] = z;
    }
    // ---- grid barrier (all 512 blocks co-resident) ----
    __syncthreads();
    if (tid == 0) {
      __threadfence();  // make phase-1 stores device-visible (release)
      __hip_atomic_fetch_add(ctr, 1u, __ATOMIC_ACQ_REL, __HIP_MEMORY_SCOPE_AGENT);
      unsigned long long spin = 0;
      while (__hip_atomic_load(ctr, __ATOMIC_ACQUIRE, __HIP_MEMORY_SCOPE_AGENT) < 512u) {
        if (++spin > (1ull << 30)) break;  // bounded: never triggers when co-resident
        __builtin_amdgcn_s_sleep(2);
      }
      __threadfence();  // acquire: invalidate stale cache lines before ws reads
    }
    __syncthreads();
  }

  const int l = tid & 63;
  const int w = tid >> 6;
  const int lane15 = l & 15;
  const int q = l >> 4;
  const int wm = w >> 1;   // 2x2 wave grid, each wave 64x64
  const int wn = w & 1;

  const int rhalf = bid & 1;          // XCD swizzle: (rhalf, ob) const per XCD
  const int ob = (bid >> 1) & 3;
  const int sb = bid >> 3;
  const int s0 = sb * BM;
  const int o0 = ob * BN;
  const int r0 = rhalf * 8;

  for (int idx = tid; idx < 8 * BN; idx += 256) {
    int rr = idx >> 7, j = idx & 127;
    lds_bias[idx] = -L2E * bias_g[(r0 + rr) * OO + o0 + j];
  }
  for (int idx = tid; idx < 8 * BM; idx += 256) {
    int rr = idx >> 7, i = idx & 127;
    lds_lam[idx] = lam_g[(s0 + i) * RR + (r0 + rr)];
  }

  // staging descriptors: 4 chunks per thread per matrix per step
  // LDS chunk(row,k8) = row*8 + (k8 ^ (row&7))  (XOR swizzle)
  int goffs[4];
  int coffs[4];
#pragma unroll
  for (int i = 0; i < 4; ++i) {
    int c = (w * 4 + i) * 64 + l;
    int row = c >> 3;
    int k8 = (c & 7) ^ (row & 7);
    goffs[i] = row * DD + k8 * 8;
    coffs[i] = c * 8;
  }

  int afo[4], bfo[4];
#pragma unroll
  for (int t = 0; t < 4; ++t) {
    int ra = wm * 64 + t * 16 + lane15;
    afo[t] = (ra * 8 + (q ^ (ra & 7))) * 8;
    int rb = wn * 64 + t * 16 + lane15;
    bfo[t] = (rb * 8 + (q ^ (rb & 7))) * 8;
  }

  const __bf16* Xb = (const __bf16*)Xp;
  const __bf16* Wb = (const __bf16*)Wp;

  auto issue_pre = [&](int step, int buf) {
    int rl = step >> 4, kt = step & 15;
    const __bf16* ga = Xb + s0 * DD + kt * BK;
    const __bf16* gb = Wb + ((r0 + rl) * OO + o0) * DD + kt * BK;
#pragma unroll
    for (int i = 0; i < 4; ++i)
      gload_lds16(ga + goffs[i], &lds_a[buf][(w * 4 + i) * 512]);
#pragma unroll
    for (int i = 0; i < 4; ++i)
      gload_lds16(gb + goffs[i], &lds_b[buf][(w * 4 + i) * 512]);
  };

  float4 ra_[4][2], rb_[4][2];
  auto issue_fb = [&](int step) {
    int rl = step >> 4, kt = step & 15;
    const float* ga = Xf32 + s0 * DD + kt * BK;
    const float* gb = Wf32 + ((r0 + rl) * OO + o0) * DD + kt * BK;
#pragma unroll
    for (int i = 0; i < 4; ++i) {
      const float4* p = (const float4*)(ga + goffs[i]);
      ra_[i][0] = p[0];
      ra_[i][1] = p[1];
      const float4* pb = (const float4*)(gb + goffs[i]);
      rb_[i][0] = pb[0];
      rb_[i][1] = pb[1];
    }
  };
  auto commit_fb = [&](int buf) {
#pragma unroll
    for (int i = 0; i < 4; ++i) {
      bf16_8 t;
      t[0] = (__bf16)ra_[i][0].x; t[1] = (__bf16)ra_[i][0].y;
      t[2] = (__bf16)ra_[i][0].z; t[3] = (__bf16)ra_[i][0].w;
      t[4] = (__bf16)ra_[i][1].x; t[5] = (__bf16)ra_[i][1].y;
      t[6] = (__bf16)ra_[i][1].z; t[7] = (__bf16)ra_[i][1].w;
      *(bf16_8*)&lds_a[buf][coffs[i]] = t;
      bf16_8 u;
      u[0] = (__bf16)rb_[i][0].x; u[1] = (__bf16)rb_[i][0].y;
      u[2] = (__bf16)rb_[i][0].z; u[3] = (__bf16)rb_[i][0].w;
      u[4] = (__bf16)rb_[i][1].x; u[5] = (__bf16)rb_[i][1].y;
      u[6] = (__bf16)rb_[i][1].z; u[7] = (__bf16)rb_[i][1].w;
      *(bf16_8*)&lds_b[buf][coffs[i]] = u;
    }
  };

  f32_4 acc[4][4], oacc[4][4];
#pragma unroll
  for (int mi = 0; mi < 4; ++mi)
#pragma unroll
    for (int ni = 0; ni < 4; ++ni) {
      acc[mi][ni] = f32_4{0.f, 0.f, 0.f, 0.f};
      oacc[mi][ni] = f32_4{0.f, 0.f, 0.f, 0.f};
    }

  if constexpr (MODE != 2) {
    issue_pre(0, 0);
  } else {
    issue_fb(0);
    commit_fb(0);
  }
  __syncthreads();

  for (int step = 0; step < NSTEP; ++step) {
    const int cur = step & 1;
    const bool more = (step + 1) < NSTEP;
    if (more) {
      if constexpr (MODE != 2) issue_pre(step + 1, cur ^ 1);
      else issue_fb(step + 1);
    }

    const __bf16* A = lds_a[cur];
    const __bf16* B = lds_b[cur];
#pragma unroll
    for (int ks = 0; ks < 2; ++ks) {
      const int xr = ks ? 32 : 0;
      bf16_8 av[4], bv[4];
#pragma unroll
      for (int mi = 0; mi < 4; ++mi) av[mi] = *(const bf16_8*)(A + (afo[mi] ^ xr));
#pragma unroll
      for (int ni = 0; ni < 4; ++ni) bv[ni] = *(const bf16_8*)(B + (bfo[ni] ^ xr));
#pragma unroll
      for (int mi = 0; mi < 4; ++mi)
#pragma unroll
        for (int ni = 0; ni < 4; ++ni)
          acc[mi][ni] =
              __builtin_amdgcn_mfma_f32_16x16x32_bf16(av[mi], bv[ni], acc[mi][ni], 0, 0, 0);
    }

    if constexpr (MODE == 2) {
      if (more) commit_fb(cur ^ 1);
    }

    if ((step & 15) == 15) {  // rule rl finished K: fused sigmoid + lambda-reduce
      const int rl = step >> 4;
      float lamv[4][4];
#pragma unroll
      for (int mi = 0; mi < 4; ++mi)
#pragma unroll
        for (int v = 0; v < 4; ++v)
          lamv[mi][v] = lds_lam[rl * BM + wm * 64 + mi * 16 + q * 4 + v];
#pragma unroll
      for (int ni = 0; ni < 4; ++ni) {
        const float nb = lds_bias[rl * BN + wn * 64 + ni * 16 + lane15];  // -b*log2e
#pragma unroll
        for (int mi = 0; mi < 4; ++mi)
#pragma unroll
          for (int v = 0; v < 4; ++v) {
            // sigmoid(x+b) = 1/(1 + 2^(-(x+b)*log2e)) : fma, exp2, add, rcp
            float t = __builtin_fmaf(acc[mi][ni][v], -L2E, nb);
            float e = __builtin_amdgcn_exp2f(t);
            float h = __builtin_amdgcn_rcpf(1.0f + e);
            oacc[mi][ni][v] = __builtin_fmaf(lamv[mi][v], h, oacc[mi][ni][v]);
            acc[mi][ni][v] = 0.f;
          }
      }
    }
    __syncthreads();
  }

#pragma unroll
  for (int mi = 0; mi < 4; ++mi)
#pragma unroll
    for (int ni = 0; ni < 4; ++ni)
#pragma unroll
      for (int v = 0; v < 4; ++v) {
        int row = s0 + wm * 64 + mi * 16 + q * 4 + v;
        int col = o0 + wn * 64 + ni * 16 + lane15;
        atomicAdd(&out[row * OO + col], oacc[mi][ni][v]);
      }
}

extern "C" void kernel_launch(void* const* d_in, const int* in_sizes, int n_in,
                              void* d_out, int out_size, void* d_ws, size_t ws_size,
                              hipStream_t stream) {
  const float* X = (const float*)d_in[0];
  const float* W = (const float*)d_in[1];
  const float* b = (const float*)d_in[2];
  const float* lam = (const float*)d_in[3];
  float* out = (float*)d_out;

  const size_t need = (size_t)2 * SS * DD * sizeof(__bf16);  // 32 MB
  __bf16* Xb = (__bf16*)d_ws;
  __bf16* Wb = Xb + (size_t)SS * DD;

  if (ws_size >= need + 256) {
    // single fused dispatch: cvt + out-zero + grid barrier + gemm
    unsigned int* ctr = (unsigned int*)((char*)d_ws + need);
    hipMemsetAsync(ctr, 0, 64, stream);
    somfnn_gemm<0><<<dim3(512), dim3(256), 0, stream>>>(Xb, Wb, b, lam, out, X, W, ctr);
  } else if (ws_size >= need) {
    hipMemsetAsync(out, 0, (size_t)SS * OO * sizeof(float), stream);
    const int n4 = SS * DD / 4;
    somfnn_cvt<<<dim3((n4 + 255) / 256), dim3(256), 0, stream>>>(X, Xb, n4);
    somfnn_cvt<<<dim3((n4 + 255) / 256), dim3(256), 0, stream>>>(W, Wb, n4);
    somfnn_gemm<1><<<dim3(512), dim3(256), 0, stream>>>(Xb, Wb, b, lam, out, X, W, nullptr);
  } else {
    hipMemsetAsync(out, 0, (size_t)SS * OO * sizeof(float), stream);
    somfnn_gemm<2><<<dim3(512), dim3(256), 0, stream>>>(X, W, b, lam, out, X, W, nullptr);
  }
}

// Round 3
// 267.350 us; speedup vs baseline: 1.3432x; 1.3432x over previous
//
#include <hip/hip_runtime.h>
#include <hip/hip_bf16.h>
#include <stdint.h>

#define SS 8192
#define DD 1024
#define RR 16
#define OO 512

typedef __bf16 bf16_8 __attribute__((ext_vector_type(8)));
typedef __bf16 bf16_4 __attribute__((ext_vector_type(4)));
typedef float f32_4 __attribute__((ext_vector_type(4)));

typedef __attribute__((address_space(1))) void g1_void;
typedef __attribute__((address_space(3))) void lds_void;

#define L2E 1.44269504f

__device__ __forceinline__ void gload_lds16(const void* g, void* l) {
  __builtin_amdgcn_global_load_lds((g1_void*)(uintptr_t)g,
                                   (lds_void*)(uint32_t)(uintptr_t)l, 16, 0, 0);
}

// One prep dispatch: cvt X->bf16, cvt W->bf16, zero out. Replaces
// memset + 2 cvt kernels (3 graph nodes -> 1; each node gap was ~15-25us).
__global__ __launch_bounds__(256) void somfnn_prep(
    const float4* __restrict__ X, const float4* __restrict__ W,
    bf16_4* __restrict__ Xb, bf16_4* __restrict__ Wb, float4* __restrict__ out) {
  const int t = blockIdx.x * 256 + threadIdx.x;   // grid 2048*256 = 524288
  constexpr int NF4 = SS * DD / 4;                // 2M float4 each for X, W
#pragma unroll
  for (int it = 0; it < 4; ++it) {
    int i = it * 524288 + t;
    float4 v = X[i];
    bf16_4 o;
    o[0] = (__bf16)v.x; o[1] = (__bf16)v.y; o[2] = (__bf16)v.z; o[3] = (__bf16)v.w;
    Xb[i] = o;
  }
#pragma unroll
  for (int it = 0; it < 4; ++it) {
    int i = it * 524288 + t;
    float4 v = W[i];
    bf16_4 o;
    o[0] = (__bf16)v.x; o[1] = (__bf16)v.y; o[2] = (__bf16)v.z; o[3] = (__bf16)v.w;
    Wb[i] = o;
  }
  (void)NF4;
  float4 z{0.f, 0.f, 0.f, 0.f};
#pragma unroll
  for (int it = 0; it < 2; ++it) out[it * 524288 + t] = z;  // 1M float4 = 16MB
}

// MODE 1: preconv — bf16 GEMM from ws (prep kernel ran before). Proven 165.7us.
// MODE 2: fallback — fp32 inputs, convert during LDS staging (correctness path).
template <int MODE>
__global__ __launch_bounds__(256, 2) void somfnn_gemm(
    const void* __restrict__ Xp, const void* __restrict__ Wp,
    const float* __restrict__ bias_g, const float* __restrict__ lam_g,
    float* __restrict__ out,
    const float* __restrict__ Xf32, const float* __restrict__ Wf32) {
  constexpr int BM = 128, BN = 128, BK = 64;
  constexpr int TILE = BM * BK;          // 8192 bf16 = 16KB
  constexpr int NSTEP = 8 * (DD / BK);   // 8 rules * 16 k-tiles = 128

  __shared__ __align__(16) __bf16 lds_a[2][TILE];
  __shared__ __align__(16) __bf16 lds_b[2][TILE];
  __shared__ float lds_bias[8 * BN];   // pre-scaled: -b * log2(e)
  __shared__ float lds_lam[8 * BM];

  const int tid = threadIdx.x;
  const int bid = blockIdx.x;

  const int l = tid & 63;
  const int w = tid >> 6;
  const int lane15 = l & 15;
  const int q = l >> 4;
  const int wm = w >> 1;   // 2x2 wave grid, each wave 64x64
  const int wn = w & 1;

  const int rhalf = bid & 1;          // XCD swizzle: (rhalf, ob) const per XCD
  const int ob = (bid >> 1) & 3;
  const int sb = bid >> 3;
  const int s0 = sb * BM;
  const int o0 = ob * BN;
  const int r0 = rhalf * 8;

  for (int idx = tid; idx < 8 * BN; idx += 256) {
    int rr = idx >> 7, j = idx & 127;
    lds_bias[idx] = -L2E * bias_g[(r0 + rr) * OO + o0 + j];
  }
  for (int idx = tid; idx < 8 * BM; idx += 256) {
    int rr = idx >> 7, i = idx & 127;
    lds_lam[idx] = lam_g[(s0 + i) * RR + (r0 + rr)];
  }

  // staging descriptors: 4 chunks per thread per matrix per step
  // LDS chunk(row,k8) = row*8 + (k8 ^ (row&7))  (XOR swizzle: conflict-free
  // ds_read_b128 AND contiguous lane-order fill for global_load_lds)
  int goffs[4];
  int coffs[4];
#pragma unroll
  for (int i = 0; i < 4; ++i) {
    int c = (w * 4 + i) * 64 + l;
    int row = c >> 3;
    int k8 = (c & 7) ^ (row & 7);
    goffs[i] = row * DD + k8 * 8;
    coffs[i] = c * 8;
  }

  int afo[4], bfo[4];
#pragma unroll
  for (int t = 0; t < 4; ++t) {
    int ra = wm * 64 + t * 16 + lane15;
    afo[t] = (ra * 8 + (q ^ (ra & 7))) * 8;
    int rb = wn * 64 + t * 16 + lane15;
    bfo[t] = (rb * 8 + (q ^ (rb & 7))) * 8;
  }

  const __bf16* Xb = (const __bf16*)Xp;
  const __bf16* Wb = (const __bf16*)Wp;

  auto issue_pre = [&](int step, int buf) {
    int rl = step >> 4, kt = step & 15;
    const __bf16* ga = Xb + s0 * DD + kt * BK;
    const __bf16* gb = Wb + ((r0 + rl) * OO + o0) * DD + kt * BK;
#pragma unroll
    for (int i = 0; i < 4; ++i)
      gload_lds16(ga + goffs[i], &lds_a[buf][(w * 4 + i) * 512]);
#pragma unroll
    for (int i = 0; i < 4; ++i)
      gload_lds16(gb + goffs[i], &lds_b[buf][(w * 4 + i) * 512]);
  };

  float4 ra_[4][2], rb_[4][2];
  auto issue_fb = [&](int step) {
    int rl = step >> 4, kt = step & 15;
    const float* ga = Xf32 + s0 * DD + kt * BK;
    const float* gb = Wf32 + ((r0 + rl) * OO + o0) * DD + kt * BK;
#pragma unroll
    for (int i = 0; i < 4; ++i) {
      const float4* p = (const float4*)(ga + goffs[i]);
      ra_[i][0] = p[0];
      ra_[i][1] = p[1];
      const float4* pb = (const float4*)(gb + goffs[i]);
      rb_[i][0] = pb[0];
      rb_[i][1] = pb[1];
    }
  };
  auto commit_fb = [&](int buf) {
#pragma unroll
    for (int i = 0; i < 4; ++i) {
      bf16_8 t;
      t[0] = (__bf16)ra_[i][0].x; t[1] = (__bf16)ra_[i][0].y;
      t[2] = (__bf16)ra_[i][0].z; t[3] = (__bf16)ra_[i][0].w;
      t[4] = (__bf16)ra_[i][1].x; t[5] = (__bf16)ra_[i][1].y;
      t[6] = (__bf16)ra_[i][1].z; t[7] = (__bf16)ra_[i][1].w;
      *(bf16_8*)&lds_a[buf][coffs[i]] = t;
      bf16_8 u;
      u[0] = (__bf16)rb_[i][0].x; u[1] = (__bf16)rb_[i][0].y;
      u[2] = (__bf16)rb_[i][0].z; u[3] = (__bf16)rb_[i][0].w;
      u[4] = (__bf16)rb_[i][1].x; u[5] = (__bf16)rb_[i][1].y;
      u[6] = (__bf16)rb_[i][1].z; u[7] = (__bf16)rb_[i][1].w;
      *(bf16_8*)&lds_b[buf][coffs[i]] = u;
    }
  };

  f32_4 acc[4][4], oacc[4][4];
#pragma unroll
  for (int mi = 0; mi < 4; ++mi)
#pragma unroll
    for (int ni = 0; ni < 4; ++ni) {
      acc[mi][ni] = f32_4{0.f, 0.f, 0.f, 0.f};
      oacc[mi][ni] = f32_4{0.f, 0.f, 0.f, 0.f};
    }

  if constexpr (MODE == 1) {
    issue_pre(0, 0);
  } else {
    issue_fb(0);
    commit_fb(0);
  }
  __syncthreads();

  for (int step = 0; step < NSTEP; ++step) {
    const int cur = step & 1;
    const bool more = (step + 1) < NSTEP;
    if (more) {
      if constexpr (MODE == 1) issue_pre(step + 1, cur ^ 1);
      else issue_fb(step + 1);
    }

    const __bf16* A = lds_a[cur];
    const __bf16* B = lds_b[cur];
#pragma unroll
    for (int ks = 0; ks < 2; ++ks) {
      const int xr = ks ? 32 : 0;
      bf16_8 av[4], bv[4];
#pragma unroll
      for (int mi = 0; mi < 4; ++mi) av[mi] = *(const bf16_8*)(A + (afo[mi] ^ xr));
#pragma unroll
      for (int ni = 0; ni < 4; ++ni) bv[ni] = *(const bf16_8*)(B + (bfo[ni] ^ xr));
#pragma unroll
      for (int mi = 0; mi < 4; ++mi)
#pragma unroll
        for (int ni = 0; ni < 4; ++ni)
          acc[mi][ni] =
              __builtin_amdgcn_mfma_f32_16x16x32_bf16(av[mi], bv[ni], acc[mi][ni], 0, 0, 0);
    }

    if constexpr (MODE == 2) {
      if (more) commit_fb(cur ^ 1);
    }

    if ((step & 15) == 15) {  // rule rl finished K: fused sigmoid + lambda-reduce
      const int rl = step >> 4;
      float lamv[4][4];
#pragma unroll
      for (int mi = 0; mi < 4; ++mi)
#pragma unroll
        for (int v = 0; v < 4; ++v)
          lamv[mi][v] = lds_lam[rl * BM + wm * 64 + mi * 16 + q * 4 + v];
#pragma unroll
      for (int ni = 0; ni < 4; ++ni) {
        const float nb = lds_bias[rl * BN + wn * 64 + ni * 16 + lane15];  // -b*log2e
#pragma unroll
        for (int mi = 0; mi < 4; ++mi)
#pragma unroll
          for (int v = 0; v < 4; ++v) {
            // sigmoid(x+b) = 1/(1 + 2^(-(x+b)*log2e)) : fma, exp2, add, rcp
            float t = __builtin_fmaf(acc[mi][ni][v], -L2E, nb);
            float e = __builtin_amdgcn_exp2f(t);
            float h = __builtin_amdgcn_rcpf(1.0f + e);
            oacc[mi][ni][v] = __builtin_fmaf(lamv[mi][v], h, oacc[mi][ni][v]);
            acc[mi][ni][v] = 0.f;
          }
      }
    }
    __syncthreads();
  }

#pragma unroll
  for (int mi = 0; mi < 4; ++mi)
#pragma unroll
    for (int ni = 0; ni < 4; ++ni)
#pragma unroll
      for (int v = 0; v < 4; ++v) {
        int row = s0 + wm * 64 + mi * 16 + q * 4 + v;
        int col = o0 + wn * 64 + ni * 16 + lane15;
        atomicAdd(&out[row * OO + col], oacc[mi][ni][v]);
      }
}

extern "C" void kernel_launch(void* const* d_in, const int* in_sizes, int n_in,
                              void* d_out, int out_size, void* d_ws, size_t ws_size,
                              hipStream_t stream) {
  const float* X = (const float*)d_in[0];
  const float* W = (const float*)d_in[1];
  const float* b = (const float*)d_in[2];
  const float* lam = (const float*)d_in[3];
  float* out = (float*)d_out;

  const size_t need = (size_t)2 * SS * DD * sizeof(__bf16);  // 32 MB
  __bf16* Xb = (__bf16*)d_ws;
  __bf16* Wb = Xb + (size_t)SS * DD;

  if (ws_size >= need) {
    somfnn_prep<<<dim3(2048), dim3(256), 0, stream>>>(
        (const float4*)X, (const float4*)W, (bf16_4*)Xb, (bf16_4*)Wb, (float4*)out);
    somfnn_gemm<1><<<dim3(512), dim3(256), 0, stream>>>(Xb, Wb, b, lam, out, X, W);
  } else {
    hipMemsetAsync(out, 0, (size_t)SS * OO * sizeof(float), stream);
    somfnn_gemm<2><<<dim3(512), dim3(256), 0, stream>>>(X, W, b, lam, out, X, W);
  }
}

// Round 4
// 203.588 us; speedup vs baseline: 1.7639x; 1.3132x over previous
//
#include <hip/hip_runtime.h>
#include <hip/hip_bf16.h>
#include <stdint.h>

#define SS 8192
#define DD 1024
#define RR 16
#define OO 512

typedef __bf16 bf16_8 __attribute__((ext_vector_type(8)));
typedef __bf16 bf16_4 __attribute__((ext_vector_type(4)));
typedef float f32_4 __attribute__((ext_vector_type(4)));
typedef int i32_4 __attribute__((ext_vector_type(4)));

typedef __attribute__((address_space(1))) void g1_void;
typedef __attribute__((address_space(3))) void lds_void;

#define L2E 1.44269504f

__device__ __forceinline__ void gload_lds16(const void* g, void* l) {
  __builtin_amdgcn_global_load_lds((g1_void*)(uintptr_t)g,
                                   (lds_void*)(uint32_t)(uintptr_t)l, 16, 0, 0);
}

// Per-row absmax quantization to int8 + zero d_out.
// One block per row: rows 0..8191 = X, 8192..16383 = W. Row = 1024 f32.
// q = rint(x * 127/rowmax); scale = rowmax/127 so logit = acc*sA*sB.
__global__ __launch_bounds__(256) void somfnn_quant(
    const float* __restrict__ X, const float* __restrict__ W,
    char* __restrict__ Xq, char* __restrict__ Wq,
    float* __restrict__ sX, float* __restrict__ sW, float4* __restrict__ out) {
  __shared__ float red[4];
  const int r = blockIdx.x;
  const int tid = threadIdx.x;
  const bool isX = r < SS;
  const float* src = isX ? (X + (size_t)r * DD) : (W + (size_t)(r - SS) * DD);
  char* dst = isX ? (Xq + (size_t)r * DD) : (Wq + (size_t)(r - SS) * DD);

  float4 v = ((const float4*)src)[tid];
  float m = fmaxf(fmaxf(fabsf(v.x), fabsf(v.y)), fmaxf(fabsf(v.z), fabsf(v.w)));
#pragma unroll
  for (int off = 32; off > 0; off >>= 1) m = fmaxf(m, __shfl_xor(m, off, 64));
  if ((tid & 63) == 0) red[tid >> 6] = m;
  __syncthreads();
  m = fmaxf(fmaxf(red[0], red[1]), fmaxf(red[2], red[3]));
  m = fmaxf(m, 1e-20f);

  const float inv = 127.0f / m;
  int q0 = __float2int_rn(v.x * inv);
  int q1 = __float2int_rn(v.y * inv);
  int q2 = __float2int_rn(v.z * inv);
  int q3 = __float2int_rn(v.w * inv);
  int packed = (q0 & 0xff) | ((q1 & 0xff) << 8) | ((q2 & 0xff) << 16) | ((q3 & 0xff) << 24);
  ((int*)dst)[tid] = packed;

  if (tid == 0) {
    if (isX) sX[r] = m / 127.0f;
    else sW[r - SS] = m / 127.0f;
  }
  // zero 1KB slice of out per block (16384 * 1KB = 16MB)
  if (tid < 64) {
    float4 z{0.f, 0.f, 0.f, 0.f};
    out[(size_t)r * 64 + tid] = z;
  }
}

// i8 GEMM + per-row-scale dequant + sigmoid + lambda-reduce.
// Same verified geometry as the bf16 kernel: 128-row tiles, 128B rows,
// 8x16B chunks/row, XOR swizzle chunk = k16 ^ (row&7) (conflict-free for
// both global_load_lds fill and ds_read_b128 frags). BK=128 i8 bytes.
__global__ __launch_bounds__(256, 2) void somfnn_gemm_i8(
    const char* __restrict__ Xq, const char* __restrict__ Wq,
    const float* __restrict__ sX, const float* __restrict__ sW,
    const float* __restrict__ bias_g, const float* __restrict__ lam_g,
    float* __restrict__ out) {
  constexpr int BM = 128, BN = 128, BK = 128;
  constexpr int TILEB = BM * BK;        // 16384 bytes per buffer
  constexpr int NSTEP = 8 * (DD / BK);  // 8 rules * 8 k-tiles = 64

  __shared__ __align__(16) char lds_a[2][TILEB];
  __shared__ __align__(16) char lds_b[2][TILEB];
  __shared__ float lds_bias[8 * BN];   // -b * log2e, per rule
  __shared__ float lds_lam[8 * BM];
  __shared__ float lds_sB[8 * BN];     // W-row scales, per rule
  __shared__ float lds_sA[BM];         // X-row scales

  const int tid = threadIdx.x;
  const int bid = blockIdx.x;

  const int l = tid & 63;
  const int w = tid >> 6;
  const int lane15 = l & 15;
  const int q = l >> 4;
  const int wm = w >> 1;   // 2x2 wave grid, each wave 64x64
  const int wn = w & 1;

  const int rhalf = bid & 1;          // XCD swizzle: (rhalf, ob) const per XCD
  const int ob = (bid >> 1) & 3;
  const int sb = bid >> 3;
  const int s0 = sb * BM;
  const int o0 = ob * BN;
  const int r0 = rhalf * 8;

  for (int idx = tid; idx < 8 * BN; idx += 256) {
    int rr = idx >> 7, j = idx & 127;
    lds_bias[idx] = -L2E * bias_g[(r0 + rr) * OO + o0 + j];
    lds_sB[idx] = sW[(r0 + rr) * OO + o0 + j];
  }
  for (int idx = tid; idx < 8 * BM; idx += 256) {
    int rr = idx >> 7, i = idx & 127;
    lds_lam[idx] = lam_g[(s0 + i) * RR + (r0 + rr)];
  }
  if (tid < BM) lds_sA[tid] = sX[s0 + tid];

  // staging: 4 chunks of 16B per thread per matrix per step
  int goffs[4];  // global byte offset within tile: row*DD + k16*16
#pragma unroll
  for (int i = 0; i < 4; ++i) {
    int c = (w * 4 + i) * 64 + l;
    int row = c >> 3;
    int k16 = (c & 7) ^ (row & 7);
    goffs[i] = row * DD + k16 * 16;
  }

  // fragment LDS byte offsets for ks=0; ks=1 is ^64 (chunk ^4)
  int afo[4], bfo[4];
#pragma unroll
  for (int t = 0; t < 4; ++t) {
    int ra = wm * 64 + t * 16 + lane15;
    afo[t] = ra * BK + ((q ^ (ra & 7)) * 16);
    int rb = wn * 64 + t * 16 + lane15;
    bfo[t] = rb * BK + ((q ^ (rb & 7)) * 16);
  }

  auto issue_pre = [&](int step, int buf) {
    int rl = step >> 3, kt = step & 7;
    const char* ga = Xq + (size_t)s0 * DD + kt * BK;
    const char* gb = Wq + ((size_t)(r0 + rl) * OO + o0) * DD + kt * BK;
#pragma unroll
    for (int i = 0; i < 4; ++i)
      gload_lds16(ga + goffs[i], &lds_a[buf][(w * 4 + i) * 1024]);
#pragma unroll
    for (int i = 0; i < 4; ++i)
      gload_lds16(gb + goffs[i], &lds_b[buf][(w * 4 + i) * 1024]);
  };

  i32_4 acc[4][4];
  f32_4 oacc[4][4];
#pragma unroll
  for (int mi = 0; mi < 4; ++mi)
#pragma unroll
    for (int ni = 0; ni < 4; ++ni) {
      acc[mi][ni] = i32_4{0, 0, 0, 0};
      oacc[mi][ni] = f32_4{0.f, 0.f, 0.f, 0.f};
    }

  issue_pre(0, 0);
  __syncthreads();

  for (int step = 0; step < NSTEP; ++step) {
    const int cur = step & 1;
    const bool more = (step + 1) < NSTEP;
    if (more) issue_pre(step + 1, cur ^ 1);

    const char* A = lds_a[cur];
    const char* B = lds_b[cur];
#pragma unroll
    for (int ks = 0; ks < 2; ++ks) {
      const int xr = ks ? 64 : 0;
      i32_4 av[4], bv[4];
#pragma unroll
      for (int mi = 0; mi < 4; ++mi) av[mi] = *(const i32_4*)(A + (afo[mi] ^ xr));
#pragma unroll
      for (int ni = 0; ni < 4; ++ni) bv[ni] = *(const i32_4*)(B + (bfo[ni] ^ xr));
#pragma unroll
      for (int mi = 0; mi < 4; ++mi)
#pragma unroll
        for (int ni = 0; ni < 4; ++ni)
          acc[mi][ni] =
              __builtin_amdgcn_mfma_i32_16x16x64_i8(av[mi], bv[ni], acc[mi][ni], 0, 0, 0);
    }

    if ((step & 7) == 7) {  // rule rl finished K: dequant + sigmoid + reduce
      const int rl = step >> 3;
      float lsa[4][4], lamv[4][4];
#pragma unroll
      for (int mi = 0; mi < 4; ++mi)
#pragma unroll
        for (int v = 0; v < 4; ++v) {
          int ridx = wm * 64 + mi * 16 + q * 4 + v;
          lsa[mi][v] = -L2E * lds_sA[ridx];
          lamv[mi][v] = lds_lam[rl * BM + ridx];
        }
#pragma unroll
      for (int ni = 0; ni < 4; ++ni) {
        const int cidx = wn * 64 + ni * 16 + lane15;
        const float nb = lds_bias[rl * BN + cidx];
        const float sbv = lds_sB[rl * BN + cidx];
#pragma unroll
        for (int mi = 0; mi < 4; ++mi)
#pragma unroll
          for (int v = 0; v < 4; ++v) {
            // sigmoid(acc*sa*sb + b) = 1/(1 + 2^(-(logit+b)*log2e))
            float t = __builtin_fmaf((float)acc[mi][ni][v], lsa[mi][v] * sbv, nb);
            float e = __builtin_amdgcn_exp2f(t);
            float h = __builtin_amdgcn_rcpf(1.0f + e);
            oacc[mi][ni][v] = __builtin_fmaf(lamv[mi][v], h, oacc[mi][ni][v]);
            acc[mi][ni][v] = 0;
          }
      }
    }
    __syncthreads();
  }

#pragma unroll
  for (int mi = 0; mi < 4; ++mi)
#pragma unroll
    for (int ni = 0; ni < 4; ++ni)
#pragma unroll
      for (int v = 0; v < 4; ++v) {
        int row = s0 + wm * 64 + mi * 16 + q * 4 + v;
        int col = o0 + wn * 64 + ni * 16 + lane15;
        atomicAdd(&out[row * OO + col], oacc[mi][ni][v]);
      }
}

// Fallback (ws too small): bf16 GEMM converting fp32 during LDS staging.
__global__ __launch_bounds__(256, 2) void somfnn_gemm_fb(
    const float* __restrict__ Xf32, const float* __restrict__ Wf32,
    const float* __restrict__ bias_g, const float* __restrict__ lam_g,
    float* __restrict__ out) {
  constexpr int BM = 128, BN = 128, BK = 64;
  constexpr int TILE = BM * BK;
  constexpr int NSTEP = 8 * (DD / BK);

  __shared__ __align__(16) __bf16 lds_a[2][TILE];
  __shared__ __align__(16) __bf16 lds_b[2][TILE];
  __shared__ float lds_bias[8 * BN];
  __shared__ float lds_lam[8 * BM];

  const int tid = threadIdx.x;
  const int bid = blockIdx.x;
  const int l = tid & 63;
  const int w = tid >> 6;
  const int lane15 = l & 15;
  const int q = l >> 4;
  const int wm = w >> 1;
  const int wn = w & 1;

  const int rhalf = bid & 1;
  const int ob = (bid >> 1) & 3;
  const int sb = bid >> 3;
  const int s0 = sb * BM;
  const int o0 = ob * BN;
  const int r0 = rhalf * 8;

  for (int idx = tid; idx < 8 * BN; idx += 256) {
    int rr = idx >> 7, j = idx & 127;
    lds_bias[idx] = -L2E * bias_g[(r0 + rr) * OO + o0 + j];
  }
  for (int idx = tid; idx < 8 * BM; idx += 256) {
    int rr = idx >> 7, i = idx & 127;
    lds_lam[idx] = lam_g[(s0 + i) * RR + (r0 + rr)];
  }

  int goffs[4], coffs[4];
#pragma unroll
  for (int i = 0; i < 4; ++i) {
    int c = (w * 4 + i) * 64 + l;
    int row = c >> 3;
    int k8 = (c & 7) ^ (row & 7);
    goffs[i] = row * DD + k8 * 8;
    coffs[i] = c * 8;
  }
  int afo[4], bfo[4];
#pragma unroll
  for (int t = 0; t < 4; ++t) {
    int ra = wm * 64 + t * 16 + lane15;
    afo[t] = (ra * 8 + (q ^ (ra & 7))) * 8;
    int rb = wn * 64 + t * 16 + lane15;
    bfo[t] = (rb * 8 + (q ^ (rb & 7))) * 8;
  }

  float4 ra_[4][2], rb_[4][2];
  auto issue_fb = [&](int step) {
    int rl = step >> 4, kt = step & 15;
    const float* ga = Xf32 + s0 * DD + kt * BK;
    const float* gb = Wf32 + ((r0 + rl) * OO + o0) * DD + kt * BK;
#pragma unroll
    for (int i = 0; i < 4; ++i) {
      const float4* p = (const float4*)(ga + goffs[i]);
      ra_[i][0] = p[0]; ra_[i][1] = p[1];
      const float4* pb = (const float4*)(gb + goffs[i]);
      rb_[i][0] = pb[0]; rb_[i][1] = pb[1];
    }
  };
  auto commit_fb = [&](int buf) {
#pragma unroll
    for (int i = 0; i < 4; ++i) {
      bf16_8 t;
      t[0] = (__bf16)ra_[i][0].x; t[1] = (__bf16)ra_[i][0].y;
      t[2] = (__bf16)ra_[i][0].z; t[3] = (__bf16)ra_[i][0].w;
      t[4] = (__bf16)ra_[i][1].x; t[5] = (__bf16)ra_[i][1].y;
      t[6] = (__bf16)ra_[i][1].z; t[7] = (__bf16)ra_[i][1].w;
      *(bf16_8*)&lds_a[buf][coffs[i]] = t;
      bf16_8 u;
      u[0] = (__bf16)rb_[i][0].x; u[1] = (__bf16)rb_[i][0].y;
      u[2] = (__bf16)rb_[i][0].z; u[3] = (__bf16)rb_[i][0].w;
      u[4] = (__bf16)rb_[i][1].x; u[5] = (__bf16)rb_[i][1].y;
      u[6] = (__bf16)rb_[i][1].z; u[7] = (__bf16)rb_[i][1].w;
      *(bf16_8*)&lds_b[buf][coffs[i]] = u;
    }
  };

  f32_4 acc[4][4], oacc[4][4];
#pragma unroll
  for (int mi = 0; mi < 4; ++mi)
#pragma unroll
    for (int ni = 0; ni < 4; ++ni) {
      acc[mi][ni] = f32_4{0.f, 0.f, 0.f, 0.f};
      oacc[mi][ni] = f32_4{0.f, 0.f, 0.f, 0.f};
    }

  issue_fb(0);
  commit_fb(0);
  __syncthreads();

  for (int step = 0; step < NSTEP; ++step) {
    const int cur = step & 1;
    const bool more = (step + 1) < NSTEP;
    if (more) issue_fb(step + 1);

    const __bf16* A = lds_a[cur];
    const __bf16* B = lds_b[cur];
#pragma unroll
    for (int ks = 0; ks < 2; ++ks) {
      const int xr = ks ? 32 : 0;
      bf16_8 av[4], bv[4];
#pragma unroll
      for (int mi = 0; mi < 4; ++mi) av[mi] = *(const bf16_8*)(A + (afo[mi] ^ xr));
#pragma unroll
      for (int ni = 0; ni < 4; ++ni) bv[ni] = *(const bf16_8*)(B + (bfo[ni] ^ xr));
#pragma unroll
      for (int mi = 0; mi < 4; ++mi)
#pragma unroll
        for (int ni = 0; ni < 4; ++ni)
          acc[mi][ni] =
              __builtin_amdgcn_mfma_f32_16x16x32_bf16(av[mi], bv[ni], acc[mi][ni], 0, 0, 0);
    }
    if (more) commit_fb(cur ^ 1);

    if ((step & 15) == 15) {
      const int rl = step >> 4;
      float lamv[4][4];
#pragma unroll
      for (int mi = 0; mi < 4; ++mi)
#pragma unroll
        for (int v = 0; v < 4; ++v)
          lamv[mi][v] = lds_lam[rl * BM + wm * 64 + mi * 16 + q * 4 + v];
#pragma unroll
      for (int ni = 0; ni < 4; ++ni) {
        const float nb = lds_bias[rl * BN + wn * 64 + ni * 16 + lane15];
#pragma unroll
        for (int mi = 0; mi < 4; ++mi)
#pragma unroll
          for (int v = 0; v < 4; ++v) {
            float t = __builtin_fmaf(acc[mi][ni][v], -L2E, nb);
            float e = __builtin_amdgcn_exp2f(t);
            float h = __builtin_amdgcn_rcpf(1.0f + e);
            oacc[mi][ni][v] = __builtin_fmaf(lamv[mi][v], h, oacc[mi][ni][v]);
            acc[mi][ni][v] = 0.f;
          }
      }
    }
    __syncthreads();
  }

#pragma unroll
  for (int mi = 0; mi < 4; ++mi)
#pragma unroll
    for (int ni = 0; ni < 4; ++ni)
#pragma unroll
      for (int v = 0; v < 4; ++v) {
        int row = s0 + wm * 64 + mi * 16 + q * 4 + v;
        int col = o0 + wn * 64 + ni * 16 + lane15;
        atomicAdd(&out[row * OO + col], oacc[mi][ni][v]);
      }
}

extern "C" void kernel_launch(void* const* d_in, const int* in_sizes, int n_in,
                              void* d_out, int out_size, void* d_ws, size_t ws_size,
                              hipStream_t stream) {
  const float* X = (const float*)d_in[0];
  const float* W = (const float*)d_in[1];
  const float* b = (const float*)d_in[2];
  const float* lam = (const float*)d_in[3];
  float* out = (float*)d_out;

  // ws layout: Xq 8MB | Wq 8MB | sX 32KB | sW 32KB
  const size_t qbytes = (size_t)SS * DD;
  const size_t need = 2 * qbytes + 2 * (size_t)SS * sizeof(float);
  if (ws_size >= need) {
    char* Xq = (char*)d_ws;
    char* Wq = Xq + qbytes;
    float* sX = (float*)(Wq + qbytes);
    float* sW = sX + SS;
    somfnn_quant<<<dim3(2 * SS), dim3(256), 0, stream>>>(X, W, Xq, Wq, sX, sW, (float4*)out);
    somfnn_gemm_i8<<<dim3(512), dim3(256), 0, stream>>>(Xq, Wq, sX, sW, b, lam, out);
  } else {
    hipMemsetAsync(out, 0, (size_t)SS * OO * sizeof(float), stream);
    somfnn_gemm_fb<<<dim3(512), dim3(256), 0, stream>>>(X, W, b, lam, out);
  }
}